// Round 3
// baseline (461.764 us; speedup 1.0000x reference)
//
#include <hip/hip_runtime.h>
#include <hip/hip_bf16.h>

// Fused causal attention head. B=4096, T=33, C=512, DK=64.
// q=x@Wq^T, k=x@Wk^T, v=x@Wv^T, S = q k^T * C^-0.5, causal softmax, out = P v.
// fp32 in/out; bf16 internal.
//
// R7: depth-4 DMA staging via global_load_lds (m97/m201 pattern).
//  - x staged fp32 directly HBM->LDS (no VGPR round-trip, no convert-store
//    chain, no per-chunk vmcnt(0) stall). All 4 chunks issued in prologue
//    (16-17 calls/wave) -> ~68KB/block in flight -> BW-saturating.
//  - counted vmcnt(12/8/4/0) + raw s_barrier per chunk (T3+T4). W loads
//    interleaving only causes safe over-wait (DMAs are oldest, in-order).
//  - bank conflicts from 512B row stride fixed by XOR-swizzling the DMA
//    SOURCE (T2 both-sides rule): physical 16B unit = u ^ (r&7); fragment
//    reads apply the same XOR. Row 32 staged linearly (broadcast reads).
//  - fp32->bf16 at fragment read (v_cvt_pk_bf16_f32; numerics identical).
//  - LDS 67584 B -> 2 blocks/CU; __launch_bounds__(256,2) -> 256 VGPRs so
//    the compiler can deep-pipeline the per-ksl W (b-fragment) L2 loads.

typedef __attribute__((ext_vector_type(8))) short bf16x8;
typedef __attribute__((ext_vector_type(4))) float floatx4;

#define NB 4096
#define TT 33
#define CC 512

// LDS map (bytes):
//  [0, 65536): 4 chunks x rows 0-31 fp32, XOR-swizzled 16B units:
//     chunk c, row r in [0,32), unit u in [0,32):
//     off = c*16384 + r*512 + ((u ^ (r&7)) << 4)
//  [65536, 67584): row 32, 4 chunks x 512 B, linear.
// Overlay (aliases chunks 0/1; valid after QKV):
#define OFF_Q   0
#define OFF_K   4752
#define OFF_VT  9504      // 64*72*2 = 9216 -> end 18720
#define OFF_P   18720     // 3 strips x 16*72*2 -> end 25632
#define X32_OFF 65536
#define SMEM_BYTES 67584
#define QS 72             // q/k/vT/P stride (ushort): 36 dw == 4 mod 32

__device__ __forceinline__ ushort f2b(float f) {
    union { __hip_bfloat16 h; ushort u; } cv;
    cv.h = __float2bfloat16(f);   // RNE
    return cv.u;
}
__device__ __forceinline__ int imin(int a, int b) { return a < b ? a : b; }

__device__ __forceinline__ bf16x8 load8_b(const ushort* p) { return *(const bf16x8*)p; }
__device__ __forceinline__ bf16x8 cvt8(float4 f0, float4 f1) {
    bf16x8 r;
    r[0] = (short)f2b(f0.x); r[1] = (short)f2b(f0.y);
    r[2] = (short)f2b(f0.z); r[3] = (short)f2b(f0.w);
    r[4] = (short)f2b(f1.x); r[5] = (short)f2b(f1.y);
    r[6] = (short)f2b(f1.z); r[7] = (short)f2b(f1.w);
    return r;
}
__device__ __forceinline__ bf16x8 load8_f(const float* p) {
    return cvt8(*(const float4*)p, *(const float4*)(p + 4));
}

__device__ __forceinline__ void dma16(const void* g, void* l) {
    __builtin_amdgcn_global_load_lds(
        (const __attribute__((address_space(1))) void*)g,
        (__attribute__((address_space(3))) void*)l, 16, 0, 0);
}

// Prep: W (3 x [64,512] fp32) -> bf16 in ws. grid (32,3) x 256.
__global__ void conv_w_kernel(const float* __restrict__ Wq,
                              const float* __restrict__ Wk,
                              const float* __restrict__ Wv,
                              ushort* __restrict__ wb) {
    const float* src = (blockIdx.y == 0) ? Wq : (blockIdx.y == 1) ? Wk : Wv;
    int i = (blockIdx.x * 256 + threadIdx.x) * 4;
    float4 f = *(const float4*)&src[i];
    ushort4 u;
    u.x = f2b(f.x); u.y = f2b(f.y); u.z = f2b(f.z); u.w = f2b(f.w);
    *(ushort4*)&wb[(size_t)blockIdx.y * 32768 + i] = u;
}

template <bool USE_WS>
__global__ __launch_bounds__(256, 2) void head_kernel(
    const float* __restrict__ x,
    const ushort* __restrict__ wb,
    const float* __restrict__ Wqf,
    const float* __restrict__ Wkf,
    const float* __restrict__ Wvf,
    float* __restrict__ out)
{
    __shared__ __align__(16) char smem[SMEM_BYTES];
    ushort* q_s  = (ushort*)(smem + OFF_Q);
    ushort* k_s  = (ushort*)(smem + OFF_K);
    ushort* vT_s = (ushort*)(smem + OFF_VT);

    const int b    = blockIdx.x;
    const int tid  = threadIdx.x;
    const int lane = tid & 63;
    const int wave = tid >> 6;
    const int l15  = lane & 15;
    const int quad = lane >> 4;

    const float*  xg  = x + (size_t)b * (TT * CC);
    const float4* xg4 = (const float4*)xg;

    // ---- DMA prologue: issue ALL x staging (depth-4) ----
    // row 32 first (consumed by every chunk's a2): waves 0,1 stage 2 chunks each.
    if (wave < 2) {
        int cc = 2 * wave + (lane >> 5);           // chunk
        dma16(xg4 + 32 * 128 + cc * 32 + (lane & 31),
              smem + X32_OFF + wave * 1024);
    }
    // rows 0-31: wave w owns rows [w*8, w*8+8) of every chunk; 4 calls/chunk.
    #pragma unroll
    for (int c = 0; c < 4; c++) {
        #pragma unroll
        for (int t = 0; t < 4; t++) {
            int idx = wave * 256 + t * 64 + lane;  // 16B unit in rows0-31 region
            int r  = idx >> 5;
            int lu = (idx & 31) ^ (r & 7);         // pre-swizzled source unit
            dma16(xg4 + r * 128 + c * 32 + lu,
                  smem + c * 16384 + wave * 4096 + t * 1024);
        }
    }
    // Per-wave outstanding: w0/w1 = 17, w2/w3 = 16. After chunk c usable,
    // outstanding <= 12-4c for every wave (in-order retire).

    // ---- W fragment pointers (per thread) ----
    int nidx[3];
    const ushort* wrow_b[3];
    const float*  wrow_f[3];
    #pragma unroll
    for (int nl = 0; nl < 3; nl++) {
        int n = wave * 3 + nl;
        nidx[nl] = n;
        int mat = n >> 2;
        int row = (n & 3) * 16 + l15;
        if (USE_WS) {
            wrow_b[nl] = wb + (size_t)mat * 32768 + (size_t)row * CC;
            wrow_f[nl] = nullptr;
        } else {
            const float* Wf = (mat == 0) ? Wqf : (mat == 1) ? Wkf : Wvf;
            wrow_f[nl] = Wf + (size_t)row * CC;
            wrow_b[nl] = nullptr;
        }
    }

    floatx4 acc[3][3] = {};   // [m][nl]

    auto qkv_chunk = [&](int c) {
        #pragma unroll
        for (int ksl = 0; ksl < 4; ksl++) {
            int u0 = ksl * 8 + quad * 2;               // even 16B unit
            int sw = (u0 ^ (l15 & 7)) << 4;            // swizzled byte offset
            const char* base0 = smem + c * 16384 + l15 * 512;
            float4 a0lo = *(const float4*)(base0 + sw);
            float4 a0hi = *(const float4*)(base0 + (sw ^ 16));
            const char* base1 = base0 + 16 * 512;      // rows 16..31: same XOR
            float4 a1lo = *(const float4*)(base1 + sw);
            float4 a1hi = *(const float4*)(base1 + (sw ^ 16));
            const char* base2 = smem + X32_OFF + c * 512 + (u0 << 4);  // row 32
            float4 a2lo = *(const float4*)(base2);
            float4 a2hi = *(const float4*)(base2 + 16);
            bf16x8 a0 = cvt8(a0lo, a0hi);
            bf16x8 a1 = cvt8(a1lo, a1hi);
            bf16x8 a2 = cvt8(a2lo, a2hi);
            int wcol = c * 128 + ksl * 32 + quad * 8;
            bf16x8 b0 = USE_WS ? load8_b(&wrow_b[0][wcol]) : load8_f(&wrow_f[0][wcol]);
            bf16x8 b1 = USE_WS ? load8_b(&wrow_b[1][wcol]) : load8_f(&wrow_f[1][wcol]);
            bf16x8 b2 = USE_WS ? load8_b(&wrow_b[2][wcol]) : load8_f(&wrow_f[2][wcol]);
            acc[0][0] = __builtin_amdgcn_mfma_f32_16x16x32_bf16(a0, b0, acc[0][0], 0, 0, 0);
            acc[1][0] = __builtin_amdgcn_mfma_f32_16x16x32_bf16(a1, b0, acc[1][0], 0, 0, 0);
            acc[2][0] = __builtin_amdgcn_mfma_f32_16x16x32_bf16(a2, b0, acc[2][0], 0, 0, 0);
            acc[0][1] = __builtin_amdgcn_mfma_f32_16x16x32_bf16(a0, b1, acc[0][1], 0, 0, 0);
            acc[1][1] = __builtin_amdgcn_mfma_f32_16x16x32_bf16(a1, b1, acc[1][1], 0, 0, 0);
            acc[2][1] = __builtin_amdgcn_mfma_f32_16x16x32_bf16(a2, b1, acc[2][1], 0, 0, 0);
            acc[0][2] = __builtin_amdgcn_mfma_f32_16x16x32_bf16(a0, b2, acc[0][2], 0, 0, 0);
            acc[1][2] = __builtin_amdgcn_mfma_f32_16x16x32_bf16(a1, b2, acc[1][2], 0, 0, 0);
            acc[2][2] = __builtin_amdgcn_mfma_f32_16x16x32_bf16(a2, b2, acc[2][2], 0, 0, 0);
        }
    };

    // wait own DMAs for chunk c (cross-wave via barrier), then compute.
#define PHASE(c, VM)                                              \
    asm volatile("s_waitcnt vmcnt(" #VM ")" ::: "memory");        \
    __builtin_amdgcn_s_barrier();                                 \
    asm volatile("" ::: "memory");                                \
    qkv_chunk(c);

    PHASE(0, 12)
    PHASE(1, 8)
    PHASE(2, 4)
    PHASE(3, 0)
#undef PHASE

    __syncthreads();   // all waves done with QKV; chunk 0/1 regions dead

    // ---- Phase 2: zero vT strip t in [33,64), scatter q/k/vT ----
    for (int i = tid; i < 64 * 32; i += 256) {
        int d = i >> 5, t = i & 31;
        if (t) vT_s[d * QS + 32 + t] = 0;   // t = 33..63 (avoid NaN * 0 in PV)
    }
    #pragma unroll
    for (int nl = 0; nl < 3; nl++) {
        int n = nidx[nl];
        int mat = n >> 2;                  // 0=q 1=k 2=v
        int col = (n & 3) * 16 + l15;
        #pragma unroll
        for (int m = 0; m < 3; m++) {
            #pragma unroll
            for (int r = 0; r < 4; r++) {
                int row = m * 16 + quad * 4 + r;   // t (C/D layout, m89)
                if (row < TT) {
                    ushort v = f2b(acc[m][nl][r]);
                    if (mat == 0)      q_s[row * QS + col] = v;
                    else if (mat == 1) k_s[row * QS + col] = v;
                    else               vT_s[col * QS + row] = v;
                }
            }
        }
    }
    __syncthreads();   // q/k/vT complete. Tail is barrier-free.

    // ---- Tail (row-split): wave w owns S/out rows [16w, 16w+16), w<3 ----
    if (wave >= 3) return;
    const int rowbase = wave * 16;
    ushort* Pw = (ushort*)(smem + OFF_P) + wave * (16 * QS);  // wave-private strip

    // S strip = q[rows] @ k^T (all 48 padded cols)
    int qr = imin(rowbase + l15, 32);
    bf16x8 aq0 = *(const bf16x8*)&q_s[qr * QS + quad * 8];
    bf16x8 aq1 = *(const bf16x8*)&q_s[qr * QS + 32 + quad * 8];
    floatx4 s[3] = {};
    #pragma unroll
    for (int nt = 0; nt < 3; nt++) {
        int kr = imin(nt * 16 + l15, 32);
        bf16x8 bk0 = *(const bf16x8*)&k_s[kr * QS + quad * 8];
        bf16x8 bk1 = *(const bf16x8*)&k_s[kr * QS + 32 + quad * 8];
        s[nt] = __builtin_amdgcn_mfma_f32_16x16x32_bf16(aq0, bk0, s[nt], 0, 0, 0);
        s[nt] = __builtin_amdgcn_mfma_f32_16x16x32_bf16(aq1, bk1, s[nt], 0, 0, 0);
    }

    const float scale = 0.044194173824159216f;  // 512^-0.5
    #pragma unroll
    for (int nt = 0; nt < 3; nt++)
        #pragma unroll
        for (int r = 0; r < 4; r++) {
            int row = rowbase + quad * 4 + r;
            int col = nt * 16 + l15;
            float v = s[nt][r] * scale;
            s[nt][r] = (col <= row) ? v : -1e30f;
        }
    // row-wise max & sum via 16-lane butterflies (cols live on l15)
    float inv_s[4];
    #pragma unroll
    for (int r = 0; r < 4; r++) {
        float m = fmaxf(fmaxf(s[0][r], s[1][r]), s[2][r]);
        #pragma unroll
        for (int d = 1; d < 16; d <<= 1) m = fmaxf(m, __shfl_xor(m, d));
        float sum = 0.f;
        #pragma unroll
        for (int nt = 0; nt < 3; nt++) {
            float e = __expf(s[nt][r] - m);
            s[nt][r] = e;
            sum += e;
        }
        #pragma unroll
        for (int d = 1; d < 16; d <<= 1) sum += __shfl_xor(sum, d);
        inv_s[r] = 1.f / sum;
    }

    // P strip -> private LDS (16 rows x 64 cols; 33..47 are exp->0, zero 48..63)
    for (int i = lane; i < 16 * 8; i += 64) {
        int r = i >> 3, c = 48 + ((i & 7) << 1);
        *(uint*)&Pw[r * QS + c] = 0u;
    }
    #pragma unroll
    for (int nt = 0; nt < 3; nt++)
        #pragma unroll
        for (int r = 0; r < 4; r++)
            Pw[(quad * 4 + r) * QS + nt * 16 + l15] = f2b(s[nt][r]);

    // PV: out[rows, 0:64] = P_strip @ v ; 1/sum in fp32 epilogue
    bf16x8 ap0 = *(const bf16x8*)&Pw[l15 * QS + quad * 8];
    bf16x8 ap1 = *(const bf16x8*)&Pw[l15 * QS + 32 + quad * 8];
    float* og = out + (size_t)b * (TT * 64);
    #pragma unroll
    for (int nt2 = 0; nt2 < 4; nt2++) {
        int dcol = nt2 * 16 + l15;
        bf16x8 bv0 = *(const bf16x8*)&vT_s[dcol * QS + quad * 8];
        bf16x8 bv1 = *(const bf16x8*)&vT_s[dcol * QS + 32 + quad * 8];
        floatx4 o = {};
        o = __builtin_amdgcn_mfma_f32_16x16x32_bf16(ap0, bv0, o, 0, 0, 0);
        o = __builtin_amdgcn_mfma_f32_16x16x32_bf16(ap1, bv1, o, 0, 0, 0);
        #pragma unroll
        for (int r = 0; r < 4; r++) {
            int row = rowbase + quad * 4 + r;
            if (row < TT) og[row * 64 + dcol] = o[r] * inv_s[r];
        }
    }
}

extern "C" void kernel_launch(void* const* d_in, const int* in_sizes, int n_in,
                              void* d_out, int out_size, void* d_ws, size_t ws_size,
                              hipStream_t stream) {
    const float* x  = (const float*)d_in[0];
    const float* Wq = (const float*)d_in[1];
    const float* Wk = (const float*)d_in[2];
    const float* Wv = (const float*)d_in[3];
    float* out = (float*)d_out;

    if (ws_size >= 3u * 64u * 512u * sizeof(ushort)) {
        ushort* wb = (ushort*)d_ws;
        conv_w_kernel<<<dim3(32, 3), 256, 0, stream>>>(Wq, Wk, Wv, wb);
        head_kernel<true><<<NB, 256, 0, stream>>>(x, wb, nullptr, nullptr, nullptr, out);
    } else {
        head_kernel<false><<<NB, 256, 0, stream>>>(x, nullptr, Wq, Wk, Wv, out);
    }
}

// Round 4
// 428.752 us; speedup vs baseline: 1.0770x; 1.0770x over previous
//
#include <hip/hip_runtime.h>
#include <hip/hip_bf16.h>

// Fused causal attention head. B=4096, T=33, C=512, DK=64.
// q=x@Wq^T, k=x@Wk^T, v=x@Wv^T, S = q k^T * C^-0.5, causal softmax, out = P v.
// fp32 in/out; bf16 internal.
//
// R8: R7's DMA staging + R6's occupancy (the A/B showed occupancy dominated:
// R6 4blk/CU ~162us vs R7 2blk/CU 192us, both spill-free).
//  - double-buffered DMA chunks: LDS 67584 -> 34816 B => 4 blocks/CU.
//  - prologue issues row32 + chunk0 + chunk1; per chunk: vmcnt(4) + barrier,
//    compute, barrier, issue chunk c+2 into the freed buffer. vmcnt never
//    drains to 0 mid-loop (T4); prefetch distance >= 1 chunk.
//  - __launch_bounds__(256,4): 128-reg budget >= 88 measured demand (R7),
//    no spill (R7 WRITE_SIZE == out exactly).
//  - source-XOR swizzle + convert-at-read identical to R7 (harness-proven).

typedef __attribute__((ext_vector_type(8))) short bf16x8;
typedef __attribute__((ext_vector_type(4))) float floatx4;

#define NB 4096
#define TT 33
#define CC 512

// LDS map (bytes):
//  [0, 32768): 2 chunk buffers, rows 0-31 fp32, XOR-swizzled 16B units:
//     buffer (c&1), row r in [0,32), unit u in [0,32):
//     off = (c&1)*16384 + r*512 + ((u ^ (r&7)) << 4)
//  [32768, 34816): row 32, 4 chunks x 512 B, linear (staged once in prologue).
// Overlay (aliases chunk buffers; valid after QKV):
#define OFF_Q   0
#define OFF_K   4752
#define OFF_VT  9504      // 64*72*2 = 9216 -> end 18720
#define OFF_P   18720     // 3 strips x 16*72*2 -> end 25632
#define X32_OFF 32768
#define SMEM_BYTES 34816
#define QS 72             // q/k/vT/P stride (ushort): 36 dw == 4 mod 32

__device__ __forceinline__ ushort f2b(float f) {
    union { __hip_bfloat16 h; ushort u; } cv;
    cv.h = __float2bfloat16(f);   // RNE
    return cv.u;
}
__device__ __forceinline__ int imin(int a, int b) { return a < b ? a : b; }

__device__ __forceinline__ bf16x8 load8_b(const ushort* p) { return *(const bf16x8*)p; }
__device__ __forceinline__ bf16x8 cvt8(float4 f0, float4 f1) {
    bf16x8 r;
    r[0] = (short)f2b(f0.x); r[1] = (short)f2b(f0.y);
    r[2] = (short)f2b(f0.z); r[3] = (short)f2b(f0.w);
    r[4] = (short)f2b(f1.x); r[5] = (short)f2b(f1.y);
    r[6] = (short)f2b(f1.z); r[7] = (short)f2b(f1.w);
    return r;
}
__device__ __forceinline__ bf16x8 load8_f(const float* p) {
    return cvt8(*(const float4*)p, *(const float4*)(p + 4));
}

__device__ __forceinline__ void dma16(const void* g, void* l) {
    __builtin_amdgcn_global_load_lds(
        (const __attribute__((address_space(1))) void*)g,
        (__attribute__((address_space(3))) void*)l, 16, 0, 0);
}

// Prep: W (3 x [64,512] fp32) -> bf16 in ws. grid (32,3) x 256.
__global__ void conv_w_kernel(const float* __restrict__ Wq,
                              const float* __restrict__ Wk,
                              const float* __restrict__ Wv,
                              ushort* __restrict__ wb) {
    const float* src = (blockIdx.y == 0) ? Wq : (blockIdx.y == 1) ? Wk : Wv;
    int i = (blockIdx.x * 256 + threadIdx.x) * 4;
    float4 f = *(const float4*)&src[i];
    ushort4 u;
    u.x = f2b(f.x); u.y = f2b(f.y); u.z = f2b(f.z); u.w = f2b(f.w);
    *(ushort4*)&wb[(size_t)blockIdx.y * 32768 + i] = u;
}

template <bool USE_WS>
__global__ __launch_bounds__(256, 4) void head_kernel(
    const float* __restrict__ x,
    const ushort* __restrict__ wb,
    const float* __restrict__ Wqf,
    const float* __restrict__ Wkf,
    const float* __restrict__ Wvf,
    float* __restrict__ out)
{
    __shared__ __align__(16) char smem[SMEM_BYTES];
    ushort* q_s  = (ushort*)(smem + OFF_Q);
    ushort* k_s  = (ushort*)(smem + OFF_K);
    ushort* vT_s = (ushort*)(smem + OFF_VT);

    const int b    = blockIdx.x;
    const int tid  = threadIdx.x;
    const int lane = tid & 63;
    const int wave = tid >> 6;
    const int l15  = lane & 15;
    const int quad = lane >> 4;

    const float*  xg  = x + (size_t)b * (TT * CC);
    const float4* xg4 = (const float4*)xg;

    // ---- DMA helpers ----
    // rows 0-31 of chunk c: wave w owns rows [w*8, w*8+8); 4 calls/wave/chunk.
    auto issue_chunk = [&](int c) {
        #pragma unroll
        for (int t = 0; t < 4; t++) {
            int idx = wave * 256 + t * 64 + lane;  // 16B unit within chunk
            int r  = idx >> 5;
            int lu = (idx & 31) ^ (r & 7);         // pre-swizzled source unit
            dma16(xg4 + r * 128 + c * 32 + lu,
                  smem + (c & 1) * 16384 + wave * 4096 + t * 1024);
        }
    };

    // ---- prologue: row 32 (all 4 chunks) + chunks 0,1 ----
    if (wave < 2) {
        int cc = 2 * wave + (lane >> 5);           // chunk
        dma16(xg4 + 32 * 128 + cc * 32 + (lane & 31),
              smem + X32_OFF + wave * 1024);
    }
    issue_chunk(0);
    issue_chunk(1);
    // outstanding/wave: w0/w1 = 9, w2/w3 = 8. vmcnt(4) => row32 + c0 done.

    // ---- W fragment pointers (per thread) ----
    int nidx[3];
    const ushort* wrow_b[3];
    const float*  wrow_f[3];
    #pragma unroll
    for (int nl = 0; nl < 3; nl++) {
        int n = wave * 3 + nl;
        nidx[nl] = n;
        int mat = n >> 2;
        int row = (n & 3) * 16 + l15;
        if (USE_WS) {
            wrow_b[nl] = wb + (size_t)mat * 32768 + (size_t)row * CC;
            wrow_f[nl] = nullptr;
        } else {
            const float* Wf = (mat == 0) ? Wqf : (mat == 1) ? Wkf : Wvf;
            wrow_f[nl] = Wf + (size_t)row * CC;
            wrow_b[nl] = nullptr;
        }
    }

    floatx4 acc[3][3] = {};   // [m][nl]

    auto qkv_chunk = [&](int c) {
        #pragma unroll
        for (int ksl = 0; ksl < 4; ksl++) {
            int u0 = ksl * 8 + quad * 2;               // even 16B unit
            int sw = (u0 ^ (l15 & 7)) << 4;            // swizzled byte offset
            const char* base0 = smem + (c & 1) * 16384 + l15 * 512;
            float4 a0lo = *(const float4*)(base0 + sw);
            float4 a0hi = *(const float4*)(base0 + (sw ^ 16));
            const char* base1 = base0 + 16 * 512;      // rows 16..31: same XOR
            float4 a1lo = *(const float4*)(base1 + sw);
            float4 a1hi = *(const float4*)(base1 + (sw ^ 16));
            const char* base2 = smem + X32_OFF + c * 512 + (u0 << 4);  // row 32
            float4 a2lo = *(const float4*)(base2);
            float4 a2hi = *(const float4*)(base2 + 16);
            bf16x8 a0 = cvt8(a0lo, a0hi);
            bf16x8 a1 = cvt8(a1lo, a1hi);
            bf16x8 a2 = cvt8(a2lo, a2hi);
            int wcol = c * 128 + ksl * 32 + quad * 8;
            bf16x8 b0 = USE_WS ? load8_b(&wrow_b[0][wcol]) : load8_f(&wrow_f[0][wcol]);
            bf16x8 b1 = USE_WS ? load8_b(&wrow_b[1][wcol]) : load8_f(&wrow_f[1][wcol]);
            bf16x8 b2 = USE_WS ? load8_b(&wrow_b[2][wcol]) : load8_f(&wrow_f[2][wcol]);
            acc[0][0] = __builtin_amdgcn_mfma_f32_16x16x32_bf16(a0, b0, acc[0][0], 0, 0, 0);
            acc[1][0] = __builtin_amdgcn_mfma_f32_16x16x32_bf16(a1, b0, acc[1][0], 0, 0, 0);
            acc[2][0] = __builtin_amdgcn_mfma_f32_16x16x32_bf16(a2, b0, acc[2][0], 0, 0, 0);
            acc[0][1] = __builtin_amdgcn_mfma_f32_16x16x32_bf16(a0, b1, acc[0][1], 0, 0, 0);
            acc[1][1] = __builtin_amdgcn_mfma_f32_16x16x32_bf16(a1, b1, acc[1][1], 0, 0, 0);
            acc[2][1] = __builtin_amdgcn_mfma_f32_16x16x32_bf16(a2, b1, acc[2][1], 0, 0, 0);
            acc[0][2] = __builtin_amdgcn_mfma_f32_16x16x32_bf16(a0, b2, acc[0][2], 0, 0, 0);
            acc[1][2] = __builtin_amdgcn_mfma_f32_16x16x32_bf16(a1, b2, acc[1][2], 0, 0, 0);
            acc[2][2] = __builtin_amdgcn_mfma_f32_16x16x32_bf16(a2, b2, acc[2][2], 0, 0, 0);
        }
    };

#define WAITB(VM)                                                 \
    asm volatile("s_waitcnt vmcnt(" #VM ")" ::: "memory");        \
    __builtin_amdgcn_s_barrier();                                 \
    asm volatile("" ::: "memory");

    WAITB(4)  qkv_chunk(0);
    __syncthreads();  issue_chunk(2);   // buf0 free after all waves read c0
    WAITB(4)  qkv_chunk(1);
    __syncthreads();  issue_chunk(3);   // buf1 free
    WAITB(4)  qkv_chunk(2);
    WAITB(0)  qkv_chunk(3);
#undef WAITB

    __syncthreads();   // all waves done with QKV; chunk buffers dead

    // ---- Phase 2: zero vT strip t in [33,64), scatter q/k/vT ----
    for (int i = tid; i < 64 * 32; i += 256) {
        int d = i >> 5, t = i & 31;
        if (t) vT_s[d * QS + 32 + t] = 0;   // t = 33..63 (avoid NaN * 0 in PV)
    }
    #pragma unroll
    for (int nl = 0; nl < 3; nl++) {
        int n = nidx[nl];
        int mat = n >> 2;                  // 0=q 1=k 2=v
        int col = (n & 3) * 16 + l15;
        #pragma unroll
        for (int m = 0; m < 3; m++) {
            #pragma unroll
            for (int r = 0; r < 4; r++) {
                int row = m * 16 + quad * 4 + r;   // t (C/D layout, m89)
                if (row < TT) {
                    ushort v = f2b(acc[m][nl][r]);
                    if (mat == 0)      q_s[row * QS + col] = v;
                    else if (mat == 1) k_s[row * QS + col] = v;
                    else               vT_s[col * QS + row] = v;
                }
            }
        }
    }
    __syncthreads();   // q/k/vT complete. Tail is barrier-free.

    // ---- Tail (row-split): wave w owns S/out rows [16w, 16w+16), w<3 ----
    if (wave >= 3) return;
    const int rowbase = wave * 16;
    ushort* Pw = (ushort*)(smem + OFF_P) + wave * (16 * QS);  // wave-private strip

    // S strip = q[rows] @ k^T (all 48 padded cols)
    int qr = imin(rowbase + l15, 32);
    bf16x8 aq0 = *(const bf16x8*)&q_s[qr * QS + quad * 8];
    bf16x8 aq1 = *(const bf16x8*)&q_s[qr * QS + 32 + quad * 8];
    floatx4 s[3] = {};
    #pragma unroll
    for (int nt = 0; nt < 3; nt++) {
        int kr = imin(nt * 16 + l15, 32);
        bf16x8 bk0 = *(const bf16x8*)&k_s[kr * QS + quad * 8];
        bf16x8 bk1 = *(const bf16x8*)&k_s[kr * QS + 32 + quad * 8];
        s[nt] = __builtin_amdgcn_mfma_f32_16x16x32_bf16(aq0, bk0, s[nt], 0, 0, 0);
        s[nt] = __builtin_amdgcn_mfma_f32_16x16x32_bf16(aq1, bk1, s[nt], 0, 0, 0);
    }

    const float scale = 0.044194173824159216f;  // 512^-0.5
    #pragma unroll
    for (int nt = 0; nt < 3; nt++)
        #pragma unroll
        for (int r = 0; r < 4; r++) {
            int row = rowbase + quad * 4 + r;
            int col = nt * 16 + l15;
            float v = s[nt][r] * scale;
            s[nt][r] = (col <= row) ? v : -1e30f;
        }
    // row-wise max & sum via 16-lane butterflies (cols live on l15)
    float inv_s[4];
    #pragma unroll
    for (int r = 0; r < 4; r++) {
        float m = fmaxf(fmaxf(s[0][r], s[1][r]), s[2][r]);
        #pragma unroll
        for (int d = 1; d < 16; d <<= 1) m = fmaxf(m, __shfl_xor(m, d));
        float sum = 0.f;
        #pragma unroll
        for (int nt = 0; nt < 3; nt++) {
            float e = __expf(s[nt][r] - m);
            s[nt][r] = e;
            sum += e;
        }
        #pragma unroll
        for (int d = 1; d < 16; d <<= 1) sum += __shfl_xor(sum, d);
        inv_s[r] = 1.f / sum;
    }

    // P strip -> private LDS (16 rows x 64 cols; 33..47 are exp->0, zero 48..63)
    for (int i = lane; i < 16 * 8; i += 64) {
        int r = i >> 3, c = 48 + ((i & 7) << 1);
        *(uint*)&Pw[r * QS + c] = 0u;
    }
    #pragma unroll
    for (int nt = 0; nt < 3; nt++)
        #pragma unroll
        for (int r = 0; r < 4; r++)
            Pw[(quad * 4 + r) * QS + nt * 16 + l15] = f2b(s[nt][r]);

    // PV: out[rows, 0:64] = P_strip @ v ; 1/sum in fp32 epilogue
    bf16x8 ap0 = *(const bf16x8*)&Pw[l15 * QS + quad * 8];
    bf16x8 ap1 = *(const bf16x8*)&Pw[l15 * QS + 32 + quad * 8];
    float* og = out + (size_t)b * (TT * 64);
    #pragma unroll
    for (int nt2 = 0; nt2 < 4; nt2++) {
        int dcol = nt2 * 16 + l15;
        bf16x8 bv0 = *(const bf16x8*)&vT_s[dcol * QS + quad * 8];
        bf16x8 bv1 = *(const bf16x8*)&vT_s[dcol * QS + 32 + quad * 8];
        floatx4 o = {};
        o = __builtin_amdgcn_mfma_f32_16x16x32_bf16(ap0, bv0, o, 0, 0, 0);
        o = __builtin_amdgcn_mfma_f32_16x16x32_bf16(ap1, bv1, o, 0, 0, 0);
        #pragma unroll
        for (int r = 0; r < 4; r++) {
            int row = rowbase + quad * 4 + r;
            if (row < TT) og[row * 64 + dcol] = o[r] * inv_s[r];
        }
    }
}

extern "C" void kernel_launch(void* const* d_in, const int* in_sizes, int n_in,
                              void* d_out, int out_size, void* d_ws, size_t ws_size,
                              hipStream_t stream) {
    const float* x  = (const float*)d_in[0];
    const float* Wq = (const float*)d_in[1];
    const float* Wk = (const float*)d_in[2];
    const float* Wv = (const float*)d_in[3];
    float* out = (float*)d_out;

    if (ws_size >= 3u * 64u * 512u * sizeof(ushort)) {
        ushort* wb = (ushort*)d_ws;
        conv_w_kernel<<<dim3(32, 3), 256, 0, stream>>>(Wq, Wk, Wv, wb);
        head_kernel<true><<<NB, 256, 0, stream>>>(x, wb, nullptr, nullptr, nullptr, out);
    } else {
        head_kernel<false><<<NB, 256, 0, stream>>>(x, nullptr, Wq, Wk, Wv, out);
    }
}